// Round 2
// baseline (5131.414 us; speedup 1.0000x reference)
//
#include <hip/hip_runtime.h>

constexpr int NN = 100000;   // nodes
constexpr int NE = 1600000;  // edges
constexpr int NG = 5000;     // graphs

// ---------------- zero workspace ----------------
__global__ __launch_bounds__(256) void k_zero(float4* p, int n4) {
  int i = blockIdx.x * 256 + threadIdx.x;
  if (i < n4) p[i] = make_float4(0.f, 0.f, 0.f, 0.f);
}

// ---------------- edge MLP + scatter to nodes ----------------
// msg = relu([na[src], na[dst], ea[e]] @ Wm + bm);  x[dst] += msg
// unsafeAtomicAdd -> native global_atomic_add_f32 (fire-and-forget, no CAS loop)
__global__ __launch_bounds__(256, 3) void k_edge(
    const int* __restrict__ ei,
    const float* __restrict__ nattr,
    const float* __restrict__ eattr,
    const float* __restrict__ Wm,
    const float* __restrict__ bm,
    float* __restrict__ x) {
  __shared__ float Wl[960];   // 48 x 20
  __shared__ float bl[20];
  for (int i = threadIdx.x; i < 960; i += 256) Wl[i] = Wm[i];
  if (threadIdx.x < 20) bl[threadIdx.x] = bm[threadIdx.x];
  __syncthreads();

  int e = blockIdx.x * 256 + threadIdx.x;
  if (e >= NE) return;
  int src = ei[e];
  int dst = ei[NE + e];

  alignas(16) float f[48];
  float4* fv = (float4*)f;
  const float4* ps = (const float4*)(nattr + (size_t)src * 16);
  const float4* pd = (const float4*)(nattr + (size_t)dst * 16);
  const float4* pe = (const float4*)(eattr + (size_t)e * 16);
  fv[0] = ps[0]; fv[1] = ps[1]; fv[2]  = ps[2]; fv[3]  = ps[3];
  fv[4] = pd[0]; fv[5] = pd[1]; fv[6]  = pd[2]; fv[7]  = pd[3];
  fv[8] = pe[0]; fv[9] = pe[1]; fv[10] = pe[2]; fv[11] = pe[3];

  float acc[20];
#pragma unroll
  for (int j = 0; j < 20; ++j) acc[j] = bl[j];
#pragma unroll
  for (int k = 0; k < 48; ++k) {
    float fk = f[k];
#pragma unroll
    for (int jv = 0; jv < 5; ++jv) {
      // uniform LDS address across the wave -> broadcast, no bank cost
      float4 w = *(const float4*)&Wl[k * 20 + jv * 4];
      acc[jv*4+0] = fmaf(fk, w.x, acc[jv*4+0]);
      acc[jv*4+1] = fmaf(fk, w.y, acc[jv*4+1]);
      acc[jv*4+2] = fmaf(fk, w.z, acc[jv*4+2]);
      acc[jv*4+3] = fmaf(fk, w.w, acc[jv*4+3]);
    }
  }

  float* xd = x + (size_t)dst * 20;
#pragma unroll
  for (int j = 0; j < 20; ++j) {
    float m = fmaxf(acc[j], 0.f);
    if (m > 0.f) unsafeAtomicAdd(xd + j, m);  // skip zeros: ~halves atomic traffic
  }
}

// ---------------- node MLP + pool to graphs ----------------
// y = relu(x @ W1 + b1);  g[batch[n]] += y
__global__ __launch_bounds__(256) void k_node(
    const float* __restrict__ x,
    const int* __restrict__ batch,
    const float* __restrict__ W1,
    const float* __restrict__ b1,
    float* __restrict__ g) {
  __shared__ float Wl[200];   // 20 x 10
  __shared__ float bl[10];
  if (threadIdx.x < 200) Wl[threadIdx.x] = W1[threadIdx.x];
  if (threadIdx.x < 10) bl[threadIdx.x] = b1[threadIdx.x];
  __syncthreads();

  int n = blockIdx.x * 256 + threadIdx.x;
  if (n >= NN) return;

  alignas(16) float xi[20];
  float4* xv = (float4*)xi;
  const float4* px = (const float4*)(x + (size_t)n * 20);  // 80B rows -> 16B aligned
#pragma unroll
  for (int i = 0; i < 5; ++i) xv[i] = px[i];

  float acc[10];
#pragma unroll
  for (int j = 0; j < 10; ++j) acc[j] = bl[j];
#pragma unroll
  for (int k = 0; k < 20; ++k) {
    float fk = xi[k];
#pragma unroll
    for (int j = 0; j < 10; ++j) acc[j] = fmaf(fk, Wl[k * 10 + j], acc[j]);
  }

  int b = batch[n];
  float* gd = g + (size_t)b * 10;
#pragma unroll
  for (int j = 0; j < 10; ++j) {
    float m = fmaxf(acc[j], 0.f);
    if (m > 0.f) unsafeAtomicAdd(gd + j, m);
  }
}

// ---------------- graph MLP ----------------
// out = relu(g @ W2 + b2) @ W3 + b3
__global__ __launch_bounds__(256) void k_graph(
    const float* __restrict__ g,
    const float* __restrict__ W2, const float* __restrict__ b2,
    const float* __restrict__ W3, const float* __restrict__ b3,
    float* __restrict__ out) {
  __shared__ float W2l[100], b2l[10], W3l[10];
  __shared__ float b3l;
  if (threadIdx.x < 100) W2l[threadIdx.x] = W2[threadIdx.x];
  if (threadIdx.x < 10) { b2l[threadIdx.x] = b2[threadIdx.x]; W3l[threadIdx.x] = W3[threadIdx.x]; }
  if (threadIdx.x == 0) b3l = b3[0];
  __syncthreads();

  int i = blockIdx.x * 256 + threadIdx.x;
  if (i >= NG) return;

  float gi[10];
  const float2* pg = (const float2*)(g + (size_t)i * 10);  // 40B rows -> 8B aligned
#pragma unroll
  for (int k = 0; k < 5; ++k) { float2 v = pg[k]; gi[2*k] = v.x; gi[2*k+1] = v.y; }

  float o = b3l;
#pragma unroll
  for (int j = 0; j < 10; ++j) {
    float a = b2l[j];
#pragma unroll
    for (int k = 0; k < 10; ++k) a = fmaf(gi[k], W2l[k * 10 + j], a);
    o = fmaf(fmaxf(a, 0.f), W3l[j], o);
  }
  out[i] = o;
}

extern "C" void kernel_launch(void* const* d_in, const int* in_sizes, int n_in,
                              void* d_out, int out_size, void* d_ws, size_t ws_size,
                              hipStream_t stream) {
  const int*   ei    = (const int*)  d_in[0];
  const float* nattr = (const float*)d_in[1];
  const float* eattr = (const float*)d_in[2];
  const int*   batch = (const int*)  d_in[3];
  const float* Wm    = (const float*)d_in[4];
  const float* bm    = (const float*)d_in[5];
  const float* W1    = (const float*)d_in[6];
  const float* b1    = (const float*)d_in[7];
  const float* W2    = (const float*)d_in[8];
  const float* b2    = (const float*)d_in[9];
  const float* W3    = (const float*)d_in[10];
  const float* b3    = (const float*)d_in[11];

  float* x = (float*)d_ws;             // [NN, 20] = 8,000,000 B
  float* g = x + (size_t)NN * 20;      // [NG, 10] =   200,000 B

  int n4 = (NN * 20 + NG * 10) / 4;    // 512,500 float4s, exact
  k_zero <<<(n4 + 255) / 256, 256, 0, stream>>>((float4*)d_ws, n4);
  k_edge <<<(NE + 255) / 256, 256, 0, stream>>>(ei, nattr, eattr, Wm, bm, x);
  k_node <<<(NN + 255) / 256, 256, 0, stream>>>(x, batch, W1, b1, g);
  k_graph<<<(NG + 255) / 256, 256, 0, stream>>>(g, W2, b2, W3, b3, (float*)d_out);
}

// Round 3
// 4019.459 us; speedup vs baseline: 1.2766x; 1.2766x over previous
//
#include <hip/hip_runtime.h>

constexpr int NN = 100000;   // nodes
constexpr int NE = 1600000;  // edges
constexpr int NG = 5000;     // graphs
constexpr int NBKT = 782;    // ceil(NN / 128) dst-buckets of 128 nodes
constexpr int NB = 320;      // histogram/scatter blocks
constexpr int CHUNK = 5000;  // NE / NB exact

// ---- workspace layout (4B words) ----
// x     [0          .. 2,000,000)   float  [NN,20]
// g     [2,000,000  .. 2,050,000)   float  [NG,10]
// bh    [2,050,000  .. 2,300,240)   int    [NBKT][NB]
// starts[2,300,240  .. 2,301,023)   int    [NBKT+1]
// perm  [2,301,024  .. 3,901,024)   int    [NE]
constexpr size_t OFF_G = 2000000, OFF_BH = 2050000, OFF_ST = 2300240, OFF_PM = 2301024;

// ---------------- pass A: per-block bucket histogram (+ zero g) ----------------
__global__ __launch_bounds__(256) void k_hist(const int* __restrict__ ei,
                                              int* __restrict__ bh,
                                              float* __restrict__ g) {
  __shared__ int lh[NBKT];
  for (int i = threadIdx.x; i < NBKT; i += 256) lh[i] = 0;
  __syncthreads();
  int b = blockIdx.x;
  const int* dstp = ei + NE;
  int s = b * CHUNK;
  for (int i = s + threadIdx.x; i < s + CHUNK; i += 256)
    atomicAdd(&lh[dstp[i] >> 7], 1);             // LDS int atomic: native, cheap
  int gid = b * 256 + threadIdx.x;               // zero g: 50,000 floats = 12,500 float4
  if (gid < 12500) ((float4*)g)[gid] = make_float4(0.f, 0.f, 0.f, 0.f);
  __syncthreads();
  for (int k = threadIdx.x; k < NBKT; k += 256) bh[k * NB + b] = lh[k];
}

// ---------------- pass B: scan (single block) ----------------
__global__ __launch_bounds__(1024) void k_scan(int* __restrict__ bh, int* __restrict__ starts) {
  __shared__ int s0[1024], s1[1024];
  int t = threadIdx.x;
  int tot = 0;
  if (t < NBKT) {
    const int* p = bh + t * NB;
    for (int j = 0; j < NB; j += 8) {
      int a[8];
#pragma unroll
      for (int u = 0; u < 8; ++u) a[u] = p[j + u];
#pragma unroll
      for (int u = 0; u < 8; ++u) tot += a[u];
    }
  }
  int* cur = s0; int* nxt = s1;
  cur[t] = tot;
  __syncthreads();
  for (int off = 1; off < 1024; off <<= 1) {       // Hillis-Steele inclusive scan
    int v = cur[t];
    if (t >= off) v += cur[t - off];
    nxt[t] = v;
    __syncthreads();
    int* tmp = cur; cur = nxt; nxt = tmp;
  }
  int excl = cur[t] - tot;
  if (t < NBKT) {
    starts[t] = excl;
    int run = excl;
    int* p = bh + t * NB;
    for (int j = 0; j < NB; j += 8) {
      int a[8];
#pragma unroll
      for (int u = 0; u < 8; ++u) a[u] = p[j + u];
#pragma unroll
      for (int u = 0; u < 8; ++u) { int tmp = a[u]; p[j + u] = run; run += tmp; }
    }
  }
  if (t == 0) starts[NBKT] = NE;
}

// ---------------- pass C: scatter edge ids into bucket order ----------------
__global__ __launch_bounds__(256) void k_scatter(const int* __restrict__ ei,
                                                 const int* __restrict__ bh,
                                                 int* __restrict__ perm) {
  __shared__ int base[NBKT];
  __shared__ int cnt[NBKT];
  int b = blockIdx.x;
  for (int k = threadIdx.x; k < NBKT; k += 256) { base[k] = bh[k * NB + b]; cnt[k] = 0; }
  __syncthreads();
  const int* dstp = ei + NE;
  int s = b * CHUNK;
  for (int i = s + threadIdx.x; i < s + CHUNK; i += 256) {
    int d = dstp[i];
    int k = d >> 7;
    int r = atomicAdd(&cnt[k], 1);               // LDS atomic; order within bucket irrelevant
    perm[base[k] + r] = i | ((d & 127) << 24);   // pack edge id (21b) + dst low7
  }
}

// ---------------- pass D: edge MLP + LDS-tile scatter (NO global atomics) ----------------
__global__ __launch_bounds__(256) void k_edge(
    const int* __restrict__ ei,
    const float* __restrict__ nattr,
    const float* __restrict__ eattr,
    const float* __restrict__ Wm,
    const float* __restrict__ bm,
    const int* __restrict__ perm,
    const int* __restrict__ starts,
    float* __restrict__ x) {
  __shared__ float Wl[960];        // 48 x 20
  __shared__ float bl[20];
  __shared__ float xt[20 * 128];   // feature-major tile: xt[j][node], 2-lanes/bank = free
  __shared__ int s_se[2];
  for (int i = threadIdx.x; i < 960; i += 256) Wl[i] = Wm[i];
  if (threadIdx.x < 20) bl[threadIdx.x] = bm[threadIdx.x];
  for (int i = threadIdx.x; i < 2560; i += 256) xt[i] = 0.f;
  int bkt = blockIdx.x;
  if (threadIdx.x < 2) s_se[threadIdx.x] = starts[bkt + threadIdx.x];
  __syncthreads();
  int is = s_se[0], ie = s_se[1];
  int nbase = bkt * 128;

  for (int i = is + threadIdx.x; i < ie; i += 256) {
    int p = perm[i];
    int e = p & 0x00FFFFFF;
    int dl = (p >> 24) & 127;
    int src = ei[e];

    alignas(16) float f[48];
    float4* fv = (float4*)f;
    const float4* ps = (const float4*)(nattr + (size_t)src * 16);
    const float4* pd = (const float4*)(nattr + (size_t)(nbase + dl) * 16);
    const float4* pe = (const float4*)(eattr + (size_t)e * 16);
    fv[0] = ps[0]; fv[1] = ps[1]; fv[2]  = ps[2]; fv[3]  = ps[3];
    fv[4] = pd[0]; fv[5] = pd[1]; fv[6]  = pd[2]; fv[7]  = pd[3];
    fv[8] = pe[0]; fv[9] = pe[1]; fv[10] = pe[2]; fv[11] = pe[3];

    float acc[20];
#pragma unroll
    for (int j = 0; j < 20; ++j) acc[j] = bl[j];
#pragma unroll
    for (int k = 0; k < 48; ++k) {
      float fk = f[k];
#pragma unroll
      for (int jv = 0; jv < 5; ++jv) {
        float4 w = *(const float4*)&Wl[k * 20 + jv * 4];   // wave-uniform -> broadcast
        acc[jv*4+0] = fmaf(fk, w.x, acc[jv*4+0]);
        acc[jv*4+1] = fmaf(fk, w.y, acc[jv*4+1]);
        acc[jv*4+2] = fmaf(fk, w.z, acc[jv*4+2]);
        acc[jv*4+3] = fmaf(fk, w.w, acc[jv*4+3]);
      }
    }
#pragma unroll
    for (int j = 0; j < 20; ++j) {
      float m = fmaxf(acc[j], 0.f);
      if (m > 0.f) atomicAdd(&xt[j * 128 + dl], m);        // LDS fp atomic (ds_add_f32)
    }
  }
  __syncthreads();

  int nn = min(128, NN - nbase);
  int tot = nn * 20;
  float* xo = x + (size_t)nbase * 20;
  for (int idx = threadIdx.x; idx < tot; idx += 256) {     // coalesced plain stores
    int node = idx / 20;
    int j = idx - node * 20;
    xo[idx] = xt[j * 128 + node];
  }
}

// ---------------- node MLP + pool to graphs (sorted batch -> LDS partials) ----------------
constexpr int SPAN = 512;
__global__ __launch_bounds__(256) void k_node(
    const float* __restrict__ x,
    const int* __restrict__ batch,
    const float* __restrict__ W1,
    const float* __restrict__ b1,
    float* __restrict__ g) {
  __shared__ float Wl[200];
  __shared__ float bl[10];
  __shared__ float gacc[SPAN * 10];
  __shared__ int s_bmin;
  if (threadIdx.x < 200) Wl[threadIdx.x] = W1[threadIdx.x];
  if (threadIdx.x < 10) bl[threadIdx.x] = b1[threadIdx.x];
  for (int i = threadIdx.x; i < SPAN * 10; i += 256) gacc[i] = 0.f;
  int n0 = blockIdx.x * 256;
  if (threadIdx.x == 0) s_bmin = batch[n0];
  __syncthreads();
  int bmin = s_bmin;
  int n = n0 + threadIdx.x;
  if (n < NN) {
    alignas(16) float xi[20];
    float4* xv = (float4*)xi;
    const float4* px = (const float4*)(x + (size_t)n * 20);
#pragma unroll
    for (int i = 0; i < 5; ++i) xv[i] = px[i];
    float acc[10];
#pragma unroll
    for (int j = 0; j < 10; ++j) acc[j] = bl[j];
#pragma unroll
    for (int k = 0; k < 20; ++k) {
      float fk = xi[k];
#pragma unroll
      for (int j = 0; j < 10; ++j) acc[j] = fmaf(fk, Wl[k * 10 + j], acc[j]);
    }
    int bn = batch[n];
    int d = bn - bmin;
    if (d < SPAN) {
#pragma unroll
      for (int j = 0; j < 10; ++j) {
        float m = fmaxf(acc[j], 0.f);
        if (m > 0.f) atomicAdd(&gacc[d * 10 + j], m);      // LDS
      }
    } else {                                               // pathological span (empty graphs)
#pragma unroll
      for (int j = 0; j < 10; ++j) {
        float m = fmaxf(acc[j], 0.f);
        if (m > 0.f) unsafeAtomicAdd(&g[(size_t)bn * 10 + j], m);
      }
    }
  }
  __syncthreads();
  int lim = min(SPAN * 10, NG * 10 - bmin * 10);
  float* gp = g + (size_t)bmin * 10;
  for (int idx = threadIdx.x; idx < lim; idx += 256) {
    float v = gacc[idx];
    if (v != 0.f) unsafeAtomicAdd(&gp[idx], v);            // ~150 sparse atomics/block
  }
}

// ---------------- graph MLP ----------------
__global__ __launch_bounds__(256) void k_graph(
    const float* __restrict__ g,
    const float* __restrict__ W2, const float* __restrict__ b2,
    const float* __restrict__ W3, const float* __restrict__ b3,
    float* __restrict__ out) {
  __shared__ float W2l[100], b2l[10], W3l[10];
  __shared__ float b3l;
  if (threadIdx.x < 100) W2l[threadIdx.x] = W2[threadIdx.x];
  if (threadIdx.x < 10) { b2l[threadIdx.x] = b2[threadIdx.x]; W3l[threadIdx.x] = W3[threadIdx.x]; }
  if (threadIdx.x == 0) b3l = b3[0];
  __syncthreads();
  int i = blockIdx.x * 256 + threadIdx.x;
  if (i >= NG) return;
  float gi[10];
  const float2* pg = (const float2*)(g + (size_t)i * 10);
#pragma unroll
  for (int k = 0; k < 5; ++k) { float2 v = pg[k]; gi[2*k] = v.x; gi[2*k+1] = v.y; }
  float o = b3l;
#pragma unroll
  for (int j = 0; j < 10; ++j) {
    float a = b2l[j];
#pragma unroll
    for (int k = 0; k < 10; ++k) a = fmaf(gi[k], W2l[k * 10 + j], a);
    o = fmaf(fmaxf(a, 0.f), W3l[j], o);
  }
  out[i] = o;
}

extern "C" void kernel_launch(void* const* d_in, const int* in_sizes, int n_in,
                              void* d_out, int out_size, void* d_ws, size_t ws_size,
                              hipStream_t stream) {
  const int*   ei    = (const int*)  d_in[0];
  const float* nattr = (const float*)d_in[1];
  const float* eattr = (const float*)d_in[2];
  const int*   batch = (const int*)  d_in[3];
  const float* Wm    = (const float*)d_in[4];
  const float* bm    = (const float*)d_in[5];
  const float* W1    = (const float*)d_in[6];
  const float* b1    = (const float*)d_in[7];
  const float* W2    = (const float*)d_in[8];
  const float* b2    = (const float*)d_in[9];
  const float* W3    = (const float*)d_in[10];
  const float* b3    = (const float*)d_in[11];

  float* x      = (float*)d_ws;
  float* g      = (float*)d_ws + OFF_G;
  int*   bh     = (int*)d_ws + OFF_BH;
  int*   starts = (int*)d_ws + OFF_ST;
  int*   perm   = (int*)d_ws + OFF_PM;

  k_hist   <<<NB, 256, 0, stream>>>(ei, bh, g);
  k_scan   <<<1, 1024, 0, stream>>>(bh, starts);
  k_scatter<<<NB, 256, 0, stream>>>(ei, bh, perm);
  k_edge   <<<NBKT, 256, 0, stream>>>(ei, nattr, eattr, Wm, bm, perm, starts, x);
  k_node   <<<(NN + 255) / 256, 256, 0, stream>>>(x, batch, W1, b1, g);
  k_graph  <<<(NG + 255) / 256, 256, 0, stream>>>(g, W2, b2, W3, b3, (float*)d_out);
}

// Round 4
// 1205.065 us; speedup vs baseline: 4.2582x; 3.3355x over previous
//
#include <hip/hip_runtime.h>

constexpr int NN = 100000;   // nodes
constexpr int NE = 1600000;  // edges
constexpr int NG = 5000;     // graphs
constexpr int BKT = 64;      // dst-nodes per bucket
constexpr int NBKT = (NN + BKT - 1) / BKT;   // 1563
constexpr int NB = 128;      // hist/scatter blocks
constexpr int CHUNK = NE / NB;               // 12500 exact

// ---- workspace layout (4B words) ----
constexpr size_t OFF_G  = 2000000;                      // g      [NG*10]
constexpr size_t OFF_BH = OFF_G + 50000;                // bh     [NB][NBKT]
constexpr size_t OFF_ST = OFF_BH + (size_t)NB * NBKT;   // starts [NBKT+1]
constexpr size_t OFF_PM = OFF_ST + NBKT + 1;            // perm   [NE]
// total = 3,851,629 words ~= 15.4 MB (<= round-3 footprint)

// ---------------- pass A: per-block bucket histogram (+ zero g) ----------------
__global__ __launch_bounds__(256) void k_hist(const int* __restrict__ ei,
                                              int* __restrict__ bh,
                                              float* __restrict__ g) {
  __shared__ int lh[NBKT];
  for (int i = threadIdx.x; i < NBKT; i += 256) lh[i] = 0;
  __syncthreads();
  const int* dstp = ei + NE;
  int s = blockIdx.x * CHUNK;
  for (int i = s + threadIdx.x; i < s + CHUNK; i += 256)
    atomicAdd(&lh[dstp[i] >> 6], 1);                    // LDS int atomic
  int gid = blockIdx.x * 256 + threadIdx.x;             // zero g: 12,500 float4
  if (gid < 12500) ((float4*)g)[gid] = make_float4(0.f, 0.f, 0.f, 0.f);
  __syncthreads();
  int* out = bh + (size_t)blockIdx.x * NBKT;            // block-major: coalesced
  for (int k = threadIdx.x; k < NBKT; k += 256) out[k] = lh[k];
}

// ---------------- pass B: scan (single block, 1024 thr, 2 buckets/thread) ----------------
__global__ __launch_bounds__(1024) void k_scan(int* __restrict__ bh, int* __restrict__ starts) {
  __shared__ int s0[1024], s1[1024];
  int t = threadIdx.x;
  int k0 = 2 * t, k1 = 2 * t + 1;
  int tot0 = 0, tot1 = 0;
  for (int b = 0; b < NB; ++b) {                        // coalesced (t-consecutive)
    const int* row = bh + (size_t)b * NBKT;
    if (k0 < NBKT) tot0 += row[k0];
    if (k1 < NBKT) tot1 += row[k1];
  }
  int ssum = tot0 + tot1;
  int* cur = s0; int* nxt = s1;
  cur[t] = ssum;
  __syncthreads();
  for (int off = 1; off < 1024; off <<= 1) {            // Hillis-Steele inclusive
    int v = cur[t];
    if (t >= off) v += cur[t - off];
    nxt[t] = v;
    __syncthreads();
    int* tmp = cur; cur = nxt; nxt = tmp;
  }
  int excl = cur[t] - ssum;
  if (k0 < NBKT) starts[k0] = excl;
  if (k1 <= NBKT) starts[k1] = excl + tot0;             // k1==NBKT writes starts[NBKT]=NE
  int run0 = excl, run1 = excl + tot0;
  for (int b = 0; b < NB; ++b) {                        // per-(block,bucket) bases
    int* row = bh + (size_t)b * NBKT;
    if (k0 < NBKT) { int v = row[k0]; row[k0] = run0; run0 += v; }
    if (k1 < NBKT) { int v = row[k1]; row[k1] = run1; run1 += v; }
  }
}

// ---------------- pass C: scatter edge ids into bucket order ----------------
__global__ __launch_bounds__(256) void k_scatter(const int* __restrict__ ei,
                                                 const int* __restrict__ bh,
                                                 int* __restrict__ perm) {
  __shared__ int base[NBKT];
  __shared__ int cnt[NBKT];
  const int* row = bh + (size_t)blockIdx.x * NBKT;
  for (int k = threadIdx.x; k < NBKT; k += 256) { base[k] = row[k]; cnt[k] = 0; }
  __syncthreads();
  const int* dstp = ei + NE;
  int s = blockIdx.x * CHUNK;
  for (int i = s + threadIdx.x; i < s + CHUNK; i += 256) {
    int d = dstp[i];
    int k = d >> 6;
    int r = atomicAdd(&cnt[k], 1);                      // LDS atomic
    perm[base[k] + r] = i | ((d & 63) << 24);           // edge id (21b) | dst-low6 <<24
  }
}

#define ST4(A, B, V) { A[B] = (V).x; A[B+1] = (V).y; A[B+2] = (V).z; A[B+3] = (V).w; }

// ---------------- pass D: edge MLP + LDS-tile scatter (no global atomics) ----------------
// Weights read via uniform constant-index global loads -> SGPR s_load (scalar pipe).
__global__ __launch_bounds__(256, 4) void k_edge(
    const int* __restrict__ ei,
    const float* __restrict__ nattr,
    const float* __restrict__ eattr,
    const float* __restrict__ Wm,
    const float* __restrict__ bm,
    const int* __restrict__ perm,
    const int* __restrict__ starts,
    float* __restrict__ x) {
  __shared__ float xt[BKT * 20];   // feature-major tile xt[j*64+dl]
  __shared__ int s_se[2];
  for (int i = threadIdx.x; i < BKT * 20; i += 256) xt[i] = 0.f;
  if (threadIdx.x < 2) s_se[threadIdx.x] = starts[blockIdx.x + threadIdx.x];
  __syncthreads();
  int is = s_se[0], ie = s_se[1];
  int nbase = blockIdx.x * BKT;

  int i  = is + (int)threadIdx.x;
  int pC = (i < ie) ? perm[i] : 0;
  int sC = (i < ie) ? ei[pC & 0xFFFFFF] : 0;
  while (i < ie) {
    int inx = i + 256;                                  // prefetch next iter's chain
    int pN = (inx < ie) ? perm[inx] : 0;
    int sN = (inx < ie) ? ei[pN & 0xFFFFFF] : 0;

    int e  = pC & 0xFFFFFF;
    int dl = (pC >> 24) & 63;
    const float4* ps = (const float4*)(nattr + (size_t)sC * 16);
    const float4* pd = (const float4*)(nattr + (size_t)(nbase + dl) * 16);
    const float4* pe = (const float4*)(eattr + (size_t)e * 16);

    float f[48];                                        // constant-index only -> SROA
    { float4 t0 = ps[0], t1 = ps[1], t2 = ps[2], t3 = ps[3];
      ST4(f, 0, t0) ST4(f, 4, t1) ST4(f, 8, t2) ST4(f, 12, t3) }
    { float4 t0 = pd[0], t1 = pd[1], t2 = pd[2], t3 = pd[3];
      ST4(f, 16, t0) ST4(f, 20, t1) ST4(f, 24, t2) ST4(f, 28, t3) }
    { float4 t0 = pe[0], t1 = pe[1], t2 = pe[2], t3 = pe[3];
      ST4(f, 32, t0) ST4(f, 36, t1) ST4(f, 40, t2) ST4(f, 44, t3) }

    float acc[20];
#pragma unroll
    for (int j = 0; j < 20; ++j) acc[j] = bm[j];        // uniform -> SGPR
#pragma unroll
    for (int k = 0; k < 48; ++k) {
      float fk = f[k];
#pragma unroll
      for (int j = 0; j < 20; ++j)
        acc[j] = fmaf(fk, Wm[k * 20 + j], acc[j]);      // uniform -> SGPR operand
    }
#pragma unroll
    for (int j = 0; j < 20; ++j) {
      float m = fmaxf(acc[j], 0.f);
      if (m > 0.f) atomicAdd(&xt[j * BKT + dl], m);     // LDS fp atomic
    }
    pC = pN; sC = sN; i = inx;
  }
  __syncthreads();

  int nn = min(BKT, NN - nbase);
  float* xo = x + (size_t)nbase * 20;
  for (int idx = threadIdx.x; idx < nn * 20; idx += 256) {  // coalesced stores
    int node = idx / 20;
    int j = idx - node * 20;
    xo[idx] = xt[j * BKT + node];
  }
}

// ---------------- node MLP + pool to graphs (sorted batch -> LDS partials) ----------------
constexpr int SPAN = 512;
__global__ __launch_bounds__(256) void k_node(
    const float* __restrict__ x,
    const int* __restrict__ batch,
    const float* __restrict__ W1,
    const float* __restrict__ b1,
    float* __restrict__ g) {
  __shared__ float gacc[SPAN * 10];
  __shared__ int s_bmin;
  for (int i = threadIdx.x; i < SPAN * 10; i += 256) gacc[i] = 0.f;
  int n0 = blockIdx.x * 256;
  if (threadIdx.x == 0) s_bmin = batch[n0];
  __syncthreads();
  int bmin = s_bmin;
  int n = n0 + threadIdx.x;
  if (n < NN) {
    float xi[20];
    const float4* px = (const float4*)(x + (size_t)n * 20);
    { float4 t0 = px[0], t1 = px[1], t2 = px[2], t3 = px[3], t4 = px[4];
      ST4(xi, 0, t0) ST4(xi, 4, t1) ST4(xi, 8, t2) ST4(xi, 12, t3) ST4(xi, 16, t4) }
    float acc[10];
#pragma unroll
    for (int j = 0; j < 10; ++j) acc[j] = b1[j];
#pragma unroll
    for (int k = 0; k < 20; ++k) {
      float fk = xi[k];
#pragma unroll
      for (int j = 0; j < 10; ++j) acc[j] = fmaf(fk, W1[k * 10 + j], acc[j]);
    }
    int bn = batch[n];
    int d = bn - bmin;
    if (d < SPAN) {
#pragma unroll
      for (int j = 0; j < 10; ++j) {
        float m = fmaxf(acc[j], 0.f);
        if (m > 0.f) atomicAdd(&gacc[d * 10 + j], m);   // LDS
      }
    } else {
#pragma unroll
      for (int j = 0; j < 10; ++j) {
        float m = fmaxf(acc[j], 0.f);
        if (m > 0.f) unsafeAtomicAdd(&g[(size_t)bn * 10 + j], m);
      }
    }
  }
  __syncthreads();
  int lim = min(SPAN * 10, NG * 10 - bmin * 10);
  float* gp = g + (size_t)bmin * 10;
  for (int idx = threadIdx.x; idx < lim; idx += 256) {
    float v = gacc[idx];
    if (v != 0.f) unsafeAtomicAdd(&gp[idx], v);         // sparse residuals
  }
}

// ---------------- graph MLP ----------------
__global__ __launch_bounds__(256) void k_graph(
    const float* __restrict__ g,
    const float* __restrict__ W2, const float* __restrict__ b2,
    const float* __restrict__ W3, const float* __restrict__ b3,
    float* __restrict__ out) {
  int i = blockIdx.x * 256 + threadIdx.x;
  if (i >= NG) return;
  float gi[10];
  const float2* pg = (const float2*)(g + (size_t)i * 10);
#pragma unroll
  for (int k = 0; k < 5; ++k) { float2 v = pg[k]; gi[2*k] = v.x; gi[2*k+1] = v.y; }
  float o = b3[0];
#pragma unroll
  for (int j = 0; j < 10; ++j) {
    float a = b2[j];
#pragma unroll
    for (int k = 0; k < 10; ++k) a = fmaf(gi[k], W2[k * 10 + j], a);
    o = fmaf(fmaxf(a, 0.f), W3[j], o);
  }
  out[i] = o;
}

extern "C" void kernel_launch(void* const* d_in, const int* in_sizes, int n_in,
                              void* d_out, int out_size, void* d_ws, size_t ws_size,
                              hipStream_t stream) {
  const int*   ei    = (const int*)  d_in[0];
  const float* nattr = (const float*)d_in[1];
  const float* eattr = (const float*)d_in[2];
  const int*   batch = (const int*)  d_in[3];
  const float* Wm    = (const float*)d_in[4];
  const float* bm    = (const float*)d_in[5];
  const float* W1    = (const float*)d_in[6];
  const float* b1    = (const float*)d_in[7];
  const float* W2    = (const float*)d_in[8];
  const float* b2    = (const float*)d_in[9];
  const float* W3    = (const float*)d_in[10];
  const float* b3    = (const float*)d_in[11];

  float* x      = (float*)d_ws;
  float* g      = (float*)d_ws + OFF_G;
  int*   bh     = (int*)d_ws + OFF_BH;
  int*   starts = (int*)d_ws + OFF_ST;
  int*   perm   = (int*)d_ws + OFF_PM;

  k_hist   <<<NB, 256, 0, stream>>>(ei, bh, g);
  k_scan   <<<1, 1024, 0, stream>>>(bh, starts);
  k_scatter<<<NB, 256, 0, stream>>>(ei, bh, perm);
  k_edge   <<<NBKT, 256, 0, stream>>>(ei, nattr, eattr, Wm, bm, perm, starts, x);
  k_node   <<<(NN + 255) / 256, 256, 0, stream>>>(x, batch, W1, b1, g);
  k_graph  <<<(NG + 255) / 256, 256, 0, stream>>>(g, W2, b2, W3, b3, (float*)d_out);
}